// Round 6
// baseline (272.336 us; speedup 1.0000x reference)
//
#include <hip/hip_runtime.h>
#include <hip/hip_cooperative_groups.h>
#include <stdint.h>

namespace cg = cooperative_groups;

#define BB 4
#define NN 2000
#define K_PRE 1000
#define KPAD 1024
#define MAXOUT 128
#define NMS_THR 0.3f
#define MASK_IN_VOX (28*28*28)   // 21952
#define MASK_OUT_VOX (32*32*32)  // 32768
#define STAGE_ROWS 496
#define FUSED_LDS (STAGE_ROWS * 64 * 2)   // 63488 B  (<= 64KB: coop-launch safe)
#define WALK_LDS  (KPAD * 64 * 2)         // 131072 B (fallback walk, attr opt-in)

// ==================== shared phase bodies (device functions) ================

__device__ __forceinline__ void dev_rank(int b, int chunk, int tid, float* s,
                                         const float* __restrict__ scores,
                                         const float* __restrict__ proposals,
                                         const float* __restrict__ deltas,
                                         int* __restrict__ order,
                                         float* __restrict__ boxes_ws) {
    const float* sb = scores + b * NN;
    for (int u = tid; u < NN / 4; u += 256)
        ((float4*)s)[u] = ((const float4*)sb)[u];
    __syncthreads();

    int i = chunk * 64 + (tid >> 2);
    int q = tid & 3;
    float si = (i < NN) ? s[i] : 0.f;
    int cnt = 0;
    int j0 = q * 500;
    const float4* s4 = (const float4*)s;
#pragma unroll 5
    for (int u = 0; u < 125; ++u) {
        float4 v = s4[j0 / 4 + u];
        int j = j0 + u * 4;
        cnt += (v.x > si) + (v.y > si) + (v.z > si) + (v.w > si);
        cnt += ((v.x == si) & (j + 0 < i)) + ((v.y == si) & (j + 1 < i))
             + ((v.z == si) & (j + 2 < i)) + ((v.w == si) & (j + 3 < i));
    }
    cnt += __shfl_xor(cnt, 1);
    cnt += __shfl_xor(cnt, 2);

    if (q == 0 && i < NN && cnt < K_PRE) {
        int rank = cnt;
        order[b * KPAD + rank] = i;
        const float* p = proposals + (size_t)(b * NN + i) * 6;
        const float* d = deltas    + (size_t)(b * NN + i) * 6;
        float py1 = p[0], px1 = p[1], pz1 = p[2], py2 = p[3], px2 = p[4], pz2 = p[5];
        float h = py2 - py1, w = px2 - px1, dd = pz2 - pz1;
        float cy = py1 + 0.5f * h + d[0] * h;
        float cx = px1 + 0.5f * w + d[1] * w;
        float cz = pz1 + 0.5f * dd + d[2] * dd;
        h *= expf(d[3]); w *= expf(d[4]); dd *= expf(d[5]);
        float* bw = boxes_ws + (size_t)b * 6 * KPAD + rank;
        bw[0 * KPAD] = cy - 0.5f * h;  bw[1 * KPAD] = cx - 0.5f * w;  bw[2 * KPAD] = cz - 0.5f * dd;
        bw[3 * KPAD] = cy + 0.5f * h;  bw[4 * KPAD] = cx + 0.5f * w;  bw[5 * KPAD] = cz + 0.5f * dd;
    }
}

// rowBits[(b*KPAD+k)*64+l] (uint16): bit w <=> IoU(box k, box 64w+l) > thr
__device__ __forceinline__ void dev_build(int b, int kbase, int tid, float (*sbx)[1088],
                                          const float* __restrict__ boxes_ws,
                                          unsigned short* __restrict__ rowBits) {
    const float* bw = boxes_ws + (size_t)b * 6 * KPAD;
    for (int k = tid; k < KPAD; k += 256) {
        int ks = k + (k >> 4);
#pragma unroll
        for (int c = 0; c < 6; ++c) sbx[c][ks] = bw[c * KPAD + k];
    }
    __syncthreads();
    int l = tid & 63, lr = tid >> 6;
#pragma unroll
    for (int pss = 0; pss < 4; ++pss) {
        int k = kbase + pss * 4 + lr;
        int ks = k + (k >> 4);
        float ry1 = sbx[0][ks], rx1 = sbx[1][ks], rz1 = sbx[2][ks];
        float ry2 = sbx[3][ks], rx2 = sbx[4][ks], rz2 = sbx[5][ks];
        float v1 = (ry2 - ry1) * (rx2 - rx1) * (rz2 - rz1);
        uint32_t bits = 0;
#pragma unroll
        for (int w = 0; w < 16; ++w) {
            int j = 64 * w + l;
            int js = j + (j >> 4);
            float y1 = sbx[0][js], x1 = sbx[1][js], z1 = sbx[2][js];
            float y2 = sbx[3][js], x2 = sbx[4][js], z2 = sbx[5][js];
            float iy = fmaxf(fminf(ry2, y2) - fmaxf(ry1, y1), 0.f);
            float ix = fmaxf(fminf(rx2, x2) - fmaxf(rx1, x1), 0.f);
            float iz = fmaxf(fminf(rz2, z2) - fmaxf(rz1, z1), 0.f);
            float inter = iy * ix * iz;
            float v2 = (y2 - y1) * (x2 - x1) * (z2 - z1);
            float iou = inter / (v1 + v2 - inter + 1e-8f);
            bits |= (iou > NMS_THR ? 1u : 0u) << w;
        }
        rowBits[((size_t)(b * KPAD + k)) * 64 + l] = (unsigned short)bits;
    }
}

// ballot-based greedy walk; rows [0,nstage) from LDS, rest from global (L2)
__device__ __forceinline__ void dev_walk(int b, int tid, unsigned short* rows_lds, int nstage,
                                         const unsigned short* __restrict__ rowBits,
                                         const int* __restrict__ order,
                                         const float* __restrict__ boxes_ws,
                                         float* __restrict__ out_boxes,
                                         float* __restrict__ out_bidx,
                                         int* __restrict__ g_idx,
                                         float* __restrict__ g_valid) {
    __shared__ short sel_k[MAXOUT];
    const unsigned short* rowB = rowBits + (size_t)b * KPAD * 64;
    const uint4* src4 = (const uint4*)rowB;
    uint4* dst4 = (uint4*)rows_lds;
    for (int t = tid; t < nstage * 64 * 2 / 16; t += 256) dst4[t] = src4[t];
    __syncthreads();
    if (tid < 64) {
        int lane = tid;
        // sup bit w of lane l <=> box 64w+l suppressed; pads (>=1000) pre-suppressed
        uint32_t sup = (lane >= 40) ? (1u << 15) : 0u;
        int nsel = 0;
        for (int w = 0; w < 16 && nsel < MAXOUT; ++w) {
            unsigned long long m = ~__ballot((int)((sup >> w) & 1u));
            while (m != 0ull && nsel < MAXOUT) {
                int kk = __builtin_ctzll(m);
                int k = (w << 6) + kk;                 // first unsuppressed (score order)
                unsigned short row = (k < nstage) ? rows_lds[(k << 6) + lane]
                                                  : rowB[(k << 6) + lane];
                sup |= (uint32_t)row;                  // includes self bit (IoU=1)
                if (lane == 0) sel_k[nsel] = (short)k;
                nsel++;
                m = ~__ballot((int)((sup >> w) & 1u));
            }
        }
        __builtin_amdgcn_s_waitcnt(0);  // lane0's LDS writes -> wave-visible
        const float* bw = boxes_ws + (size_t)b * 6 * KPAD;
#pragma unroll
        for (int s0 = 0; s0 < 2; ++s0) {
            int s = lane + s0 * 64;
            int valid = s < nsel;
            int k = valid ? (int)sel_k[s] : 0;
            int idx = valid ? order[b * KPAD + k] : 0;
            float vf = valid ? 1.f : 0.f;
            g_idx[b * MAXOUT + s] = idx;
            g_valid[b * MAXOUT + s] = vf;
            float* ob = out_boxes + (size_t)(b * MAXOUT + s) * 6;
#pragma unroll
            for (int c = 0; c < 6; ++c) ob[c] = bw[c * KPAD + k] * vf;
            out_bidx[b * MAXOUT + s] = (float)b;
        }
    }
}

__device__ __forceinline__ void dev_resize(int s, int tid, float* rowbuf,
                                           const float* __restrict__ masks,
                                           const int* __restrict__ g_idx,
                                           const float* __restrict__ g_valid,
                                           float* __restrict__ out_masks) {
    int b = s >> 7;
    int gi = g_idx[s];
    float vf = g_valid[s];
    const float* src = masks + (size_t)(b * NN + gi) * MASK_IN_VOX;
    float* dst = out_masks + (size_t)s * MASK_OUT_VOX;
    int lane = tid & 63;
    float* rb = rowbuf + (tid >> 6) * (64 * 36);
    const float4* s4b = (const float4*)src;

#pragma unroll
    for (int p = 0; p < 4; ++p) {
        int idx = p * 256 + tid;
        int oy = idx & 31, oz = idx >> 5;

        float syf = 0.875f * oy - 0.0625f;
        int fly = (syf >= 0.f) ? (int)syf : -1;
        float fy = syf - (float)fly;
        int y0 = fly < 0 ? 0 : fly;
        int y1 = fly + 1 > 27 ? 27 : fly + 1;

        float szf = 0.875f * oz - 0.0625f;
        int flz = (szf >= 0.f) ? (int)szf : -1;
        float fz = szf - (float)flz;
        int z0 = flz < 0 ? 0 : flz;
        int z1 = flz + 1 > 27 ? 27 : flz + 1;

        float w00 = (1.f - fy) * (1.f - fz);
        float w01 = fy * (1.f - fz);
        float w10 = (1.f - fy) * fz;
        float w11 = fy * fz;

        const float4* r00 = s4b + (z0 * 28 + y0) * 7;
        const float4* r01 = s4b + (z0 * 28 + y1) * 7;
        const float4* r10 = s4b + (z1 * 28 + y0) * 7;
        const float4* r11 = s4b + (z1 * 28 + y1) * 7;

        float c[28];
#pragma unroll
        for (int t = 0; t < 7; ++t) {
            float4 a = r00[t], bb = r01[t], cc = r10[t], dd = r11[t];
            c[4 * t + 0] = a.x * w00 + bb.x * w01 + cc.x * w10 + dd.x * w11;
            c[4 * t + 1] = a.y * w00 + bb.y * w01 + cc.y * w10 + dd.y * w11;
            c[4 * t + 2] = a.z * w00 + bb.z * w01 + cc.z * w10 + dd.z * w11;
            c[4 * t + 3] = a.w * w00 + bb.w * w01 + cc.w * w10 + dd.w * w11;
        }

#pragma unroll
        for (int e = 0; e < 8; ++e) {
            float4 o;
#pragma unroll
            for (int qq = 0; qq < 4; ++qq) {
                const int ox = e * 4 + qq;
                const float sx = 0.875f * (float)ox - 0.0625f;
                const int flx = (ox == 0) ? -1 : (14 * ox - 1) / 16;
                const float fx = sx - (float)flx;
                const int x0 = flx < 0 ? 0 : flx;
                const int x1 = flx + 1 > 27 ? 27 : flx + 1;
                (&o.x)[qq] = (c[x0] + fx * (c[x1] - c[x0])) * vf;
            }
            *(float4*)&rb[lane * 36 + e * 4] = o;
        }

        float4* dchunk = (float4*)dst + (size_t)(p * 256 + (tid & ~63)) * 8;
#pragma unroll
        for (int t = 0; t < 8; ++t) {
            int f = t * 64 + lane;
            float4 v = *(const float4*)&rb[(f >> 3) * 36 + (f & 7) * 4];
            dchunk[f] = v;
        }
    }
}

// ==================== fused cooperative kernel ==============================

__global__ __launch_bounds__(256, 1) void fused_kernel(
        const float* __restrict__ scores, const float* __restrict__ proposals,
        const float* __restrict__ deltas, const float* __restrict__ masks,
        int* __restrict__ order, float* __restrict__ boxes_ws,
        unsigned short* __restrict__ rowBits,
        int* __restrict__ g_idx, float* __restrict__ g_valid,
        float* __restrict__ out_boxes, float* __restrict__ out_masks,
        float* __restrict__ out_bidx) {
    cg::grid_group grid = cg::this_grid();
    extern __shared__ __align__(16) char smem[];
    int blk = blockIdx.x;
    int tid = threadIdx.x;

    if (blk < 128)
        dev_rank(blk >> 5, blk & 31, tid, (float*)smem, scores, proposals, deltas, order, boxes_ws);
    __threadfence(); grid.sync(); __threadfence();

    dev_build(blk >> 6, (blk & 63) * 16, tid, (float(*)[1088])smem, boxes_ws, rowBits);
    __threadfence(); grid.sync(); __threadfence();

    if (blk < BB)
        dev_walk(blk, tid, (unsigned short*)smem, STAGE_ROWS, rowBits, order, boxes_ws,
                 out_boxes, out_bidx, g_idx, g_valid);
    __threadfence(); grid.sync(); __threadfence();

    for (int r = 0; r < 2; ++r)
        dev_resize(blk * 2 + r, tid, (float*)smem, masks, g_idx, g_valid, out_masks);
}

// ==================== fallback standalone kernels (R4-proven) ===============

__global__ __launch_bounds__(256) void rank_kernel(const float* __restrict__ scores,
                                                   const float* __restrict__ proposals,
                                                   const float* __restrict__ deltas,
                                                   int* __restrict__ order,
                                                   float* __restrict__ boxes_ws) {
    __shared__ float s[NN];
    dev_rank(blockIdx.x >> 5, blockIdx.x & 31, threadIdx.x, s, scores, proposals, deltas, order, boxes_ws);
}

__global__ __launch_bounds__(256) void build_kernel(const float* __restrict__ boxes_ws,
                                                    unsigned short* __restrict__ rowBits) {
    __shared__ float sbx[6][1088];
    dev_build(blockIdx.y, blockIdx.x * 16, threadIdx.x, sbx, boxes_ws, rowBits);
}

__global__ __launch_bounds__(256) void walk_kernel(const unsigned short* __restrict__ rowBits,
                                                   const int* __restrict__ order,
                                                   const float* __restrict__ boxes_ws,
                                                   float* __restrict__ out_boxes,
                                                   float* __restrict__ out_bidx,
                                                   int* __restrict__ g_idx,
                                                   float* __restrict__ g_valid) {
    extern __shared__ unsigned short rows_lds[];
    dev_walk(blockIdx.x, threadIdx.x, rows_lds, KPAD, rowBits, order, boxes_ws,
             out_boxes, out_bidx, g_idx, g_valid);
}

__global__ __launch_bounds__(256) void resize_kernel(const float* __restrict__ masks,
                                                     const int* __restrict__ g_idx,
                                                     const float* __restrict__ g_valid,
                                                     float* __restrict__ out_masks) {
    __shared__ __align__(16) float rowbuf[4][64 * 36];
    dev_resize(blockIdx.x, threadIdx.x, &rowbuf[0][0], masks, g_idx, g_valid, out_masks);
}

// ==================== launch ================================================

extern "C" void kernel_launch(void* const* d_in, const int* in_sizes, int n_in,
                              void* d_out, int out_size, void* d_ws, size_t ws_size,
                              hipStream_t stream) {
    const float* proposals = (const float*)d_in[0];
    const float* scores    = (const float*)d_in[1];
    const float* deltas    = (const float*)d_in[2];
    const float* masks     = (const float*)d_in[3];

    float* out = (float*)d_out;
    float* out_boxes = out;                                              // [512,6]
    float* out_masks = out + (size_t)BB * MAXOUT * 6;                    // [512,32768]
    float* out_bidx  = out + (size_t)BB * MAXOUT * 6 + (size_t)BB * MAXOUT * MASK_OUT_VOX;

    char* ws = (char*)d_ws;
    int*            order    = (int*)(ws);                               // 16 KB
    int*            g_idx    = (int*)(ws + (16 << 10));                  // 2 KB
    float*          g_valid  = (float*)(ws + (18 << 10));                // 2 KB
    float*          boxes_ws = (float*)(ws + (20 << 10));                // 96 KB
    unsigned short* rowBits  = (unsigned short*)(ws + (116 << 10));      // 512 KB

    static int attr_set = 0;  // host-side, idempotent, capture-safe
    if (!attr_set) {
        hipFuncSetAttribute(reinterpret_cast<const void*>(walk_kernel),
                            hipFuncAttributeMaxDynamicSharedMemorySize, WALK_LDS);
        attr_set = 1;
    }

    // try the cooperative fused kernel; fall back to the proven 4-kernel path
    int occ = 0;
    hipError_t qe = hipOccupancyMaxActiveBlocksPerMultiprocessor(
        &occ, reinterpret_cast<const void*>(fused_kernel), 256, FUSED_LDS);
    hipError_t le = hipErrorUnknown;
    if (qe == hipSuccess && occ >= 1) {
        void* args[] = {
            (void*)&scores, (void*)&proposals, (void*)&deltas, (void*)&masks,
            (void*)&order, (void*)&boxes_ws, (void*)&rowBits,
            (void*)&g_idx, (void*)&g_valid,
            (void*)&out_boxes, (void*)&out_masks, (void*)&out_bidx
        };
        le = hipLaunchCooperativeKernel(reinterpret_cast<const void*>(fused_kernel),
                                        dim3(256), dim3(256), args, FUSED_LDS, stream);
    }
    if (le != hipSuccess) {
        rank_kernel<<<BB * 32, 256, 0, stream>>>(scores, proposals, deltas, order, boxes_ws);
        build_kernel<<<dim3(64, BB), 256, 0, stream>>>(boxes_ws, rowBits);
        walk_kernel<<<BB, 256, WALK_LDS, stream>>>(rowBits, order, boxes_ws,
                                                   out_boxes, out_bidx, g_idx, g_valid);
        resize_kernel<<<BB * MAXOUT, 256, 0, stream>>>(masks, g_idx, g_valid, out_masks);
    }
}

// Round 7
// 97.610 us; speedup vs baseline: 2.7900x; 2.7900x over previous
//
#include <hip/hip_runtime.h>
#include <stdint.h>

#define BB 4
#define NN 2000
#define K_PRE 1000
#define KPAD 1024
#define MAXOUT 128
#define NMS_THR 0.3f
#define MASK_IN_VOX (28*28*28)   // 21952
#define MASK_OUT_VOX (32*32*32)  // 32768
#define STAGE_ROWS 496
#define K1_LDS (STAGE_ROWS * 64 * 2)   // 63488 B dynamic (< 64 KB default cap)

// ---------------- agent-scope co-resident grid barrier ----------------------
// grid=256 blocks at 1/CU on 256 CUs -> all co-resident; cells zeroed per call
// by hipMemsetAsync. Release-RMW + acquire-load pair gives cross-XCD visibility.
__device__ __forceinline__ void grid_barrier(uint32_t* cell, int tid) {
    __syncthreads();
    if (tid == 0) {
        __hip_atomic_fetch_add(cell, 1u, __ATOMIC_ACQ_REL, __HIP_MEMORY_SCOPE_AGENT);
        while (__hip_atomic_load(cell, __ATOMIC_ACQUIRE, __HIP_MEMORY_SCOPE_AGENT) < 256u)
            __builtin_amdgcn_s_sleep(2);
    }
    __syncthreads();
}

// ---------------- phase bodies ----------------------------------------------

__device__ __forceinline__ void dev_rank(int b, int chunk, int tid, float* s,
                                         const float* __restrict__ scores,
                                         const float* __restrict__ proposals,
                                         const float* __restrict__ deltas,
                                         int* __restrict__ order,
                                         float* __restrict__ boxes_ws) {
    const float* sb = scores + b * NN;
    for (int u = tid; u < NN / 4; u += 256)
        ((float4*)s)[u] = ((const float4*)sb)[u];
    __syncthreads();

    int i = chunk * 64 + (tid >> 2);
    int q = tid & 3;
    float si = (i < NN) ? s[i] : 0.f;
    int cnt = 0;
    int j0 = q * 500;
    const float4* s4 = (const float4*)s;
#pragma unroll 5
    for (int u = 0; u < 125; ++u) {
        float4 v = s4[j0 / 4 + u];
        int j = j0 + u * 4;
        cnt += (v.x > si) + (v.y > si) + (v.z > si) + (v.w > si);
        cnt += ((v.x == si) & (j + 0 < i)) + ((v.y == si) & (j + 1 < i))
             + ((v.z == si) & (j + 2 < i)) + ((v.w == si) & (j + 3 < i));
    }
    cnt += __shfl_xor(cnt, 1);
    cnt += __shfl_xor(cnt, 2);

    if (q == 0 && i < NN && cnt < K_PRE) {
        int rank = cnt;
        order[b * KPAD + rank] = i;
        const float* p = proposals + (size_t)(b * NN + i) * 6;
        const float* d = deltas    + (size_t)(b * NN + i) * 6;
        float py1 = p[0], px1 = p[1], pz1 = p[2], py2 = p[3], px2 = p[4], pz2 = p[5];
        float h = py2 - py1, w = px2 - px1, dd = pz2 - pz1;
        float cy = py1 + 0.5f * h + d[0] * h;
        float cx = px1 + 0.5f * w + d[1] * w;
        float cz = pz1 + 0.5f * dd + d[2] * dd;
        h *= expf(d[3]); w *= expf(d[4]); dd *= expf(d[5]);
        float* bw = boxes_ws + (size_t)b * 6 * KPAD + rank;
        bw[0 * KPAD] = cy - 0.5f * h;  bw[1 * KPAD] = cx - 0.5f * w;  bw[2 * KPAD] = cz - 0.5f * dd;
        bw[3 * KPAD] = cy + 0.5f * h;  bw[4 * KPAD] = cx + 0.5f * w;  bw[5 * KPAD] = cz + 0.5f * dd;
    }
}

// rowBits[(b*KPAD+k)*64+l] (uint16): bit w <=> IoU(box k, box 64w+l) > thr
__device__ __forceinline__ void dev_build(int b, int kbase, int tid, float (*sbx)[1088],
                                          const float* __restrict__ boxes_ws,
                                          unsigned short* __restrict__ rowBits) {
    const float* bw = boxes_ws + (size_t)b * 6 * KPAD;
    for (int k = tid; k < KPAD; k += 256) {
        int ks = k + (k >> 4);
#pragma unroll
        for (int c = 0; c < 6; ++c) sbx[c][ks] = bw[c * KPAD + k];
    }
    __syncthreads();
    int l = tid & 63, lr = tid >> 6;
#pragma unroll
    for (int pss = 0; pss < 4; ++pss) {
        int k = kbase + pss * 4 + lr;
        int ks = k + (k >> 4);
        float ry1 = sbx[0][ks], rx1 = sbx[1][ks], rz1 = sbx[2][ks];
        float ry2 = sbx[3][ks], rx2 = sbx[4][ks], rz2 = sbx[5][ks];
        float v1 = (ry2 - ry1) * (rx2 - rx1) * (rz2 - rz1);
        uint32_t bits = 0;
#pragma unroll
        for (int w = 0; w < 16; ++w) {
            int j = 64 * w + l;
            int js = j + (j >> 4);
            float y1 = sbx[0][js], x1 = sbx[1][js], z1 = sbx[2][js];
            float y2 = sbx[3][js], x2 = sbx[4][js], z2 = sbx[5][js];
            float iy = fmaxf(fminf(ry2, y2) - fmaxf(ry1, y1), 0.f);
            float ix = fmaxf(fminf(rx2, x2) - fmaxf(rx1, x1), 0.f);
            float iz = fmaxf(fminf(rz2, z2) - fmaxf(rz1, z1), 0.f);
            float inter = iy * ix * iz;
            float v2 = (y2 - y1) * (x2 - x1) * (z2 - z1);
            float iou = inter / (v1 + v2 - inter + 1e-8f);
            bits |= (iou > NMS_THR ? 1u : 0u) << w;
        }
        rowBits[((size_t)(b * KPAD + k)) * 64 + l] = (unsigned short)bits;
    }
}

// ballot walk with depth-4 candidate prefetch; rows [0,STAGE_ROWS) from LDS
__device__ __forceinline__ void dev_walk(int b, int tid, unsigned short* rows_lds,
                                         const unsigned short* __restrict__ rowBits,
                                         const int* __restrict__ order,
                                         const float* __restrict__ boxes_ws,
                                         float* __restrict__ out_boxes,
                                         float* __restrict__ out_bidx,
                                         int* __restrict__ g_idx,
                                         float* __restrict__ g_valid) {
    __shared__ short sel_k[MAXOUT];
    const unsigned short* rowB = rowBits + (size_t)b * KPAD * 64;
    const uint4* src4 = (const uint4*)rowB;
    uint4* dst4 = (uint4*)rows_lds;
    for (int t = tid; t < STAGE_ROWS * 64 * 2 / 16; t += 256) dst4[t] = src4[t];
    __syncthreads();
    if (tid < 64) {
        int lane = tid;
        // sup bit w of lane l <=> box 64w+l suppressed; pads (>=1000) pre-suppressed
        uint32_t sup = (lane >= 40) ? (1u << 15) : 0u;
        int nsel = 0;

        auto ROW = [&](int g) -> unsigned short {
            return (g < STAGE_ROWS) ? rows_lds[(g << 6) + lane]
                                    : rowB[((size_t)g << 6) + lane];
        };

        for (int w = 0; w < 16 && nsel < MAXOUT; ++w) {
            unsigned long long m = ~__ballot((int)((sup >> w) & 1u));
            while (m != 0ull && nsel < MAXOUT) {
                unsigned long long t = m;
                int k1 = __builtin_ctzll(t); t &= t - 1;
                bool h2 = t != 0; int k2 = h2 ? __builtin_ctzll(t) : k1; t &= t - 1;
                bool h3 = t != 0; int k3 = h3 ? __builtin_ctzll(t) : k1; t &= t - 1;
                bool h4 = t != 0; int k4 = h4 ? __builtin_ctzll(t) : k1;
                int g1 = (w << 6) + k1, g2 = (w << 6) + k2;
                int g3 = (w << 6) + k3, g4 = (w << 6) + k4;
                unsigned short r1 = ROW(g1), r2 = ROW(g2), r3 = ROW(g3), r4 = ROW(g4);
                // k1 is the exact greedy pick (m is exact)
                sup |= r1; if (lane == 0) sel_k[nsel] = (short)g1; nsel++;
                m = ~__ballot((int)((sup >> w) & 1u));
                // subsequent picks valid only if they survive earlier ORs
                if (h2 && nsel < MAXOUT && ((m >> k2) & 1ull)) {
                    sup |= r2; if (lane == 0) sel_k[nsel] = (short)g2; nsel++;
                    m = ~__ballot((int)((sup >> w) & 1u));
                }
                if (h3 && nsel < MAXOUT && ((m >> k3) & 1ull)) {
                    sup |= r3; if (lane == 0) sel_k[nsel] = (short)g3; nsel++;
                    m = ~__ballot((int)((sup >> w) & 1u));
                }
                if (h4 && nsel < MAXOUT && ((m >> k4) & 1ull)) {
                    sup |= r4; if (lane == 0) sel_k[nsel] = (short)g4; nsel++;
                    m = ~__ballot((int)((sup >> w) & 1u));
                }
            }
        }
        __builtin_amdgcn_s_waitcnt(0);  // lane0's LDS writes -> wave-visible
        const float* bw = boxes_ws + (size_t)b * 6 * KPAD;
#pragma unroll
        for (int s0 = 0; s0 < 2; ++s0) {
            int s = lane + s0 * 64;
            int valid = s < nsel;
            int k = valid ? (int)sel_k[s] : 0;
            int idx = valid ? order[b * KPAD + k] : 0;
            float vf = valid ? 1.f : 0.f;
            g_idx[b * MAXOUT + s] = idx;
            g_valid[b * MAXOUT + s] = vf;
            float* ob = out_boxes + (size_t)(b * MAXOUT + s) * 6;
#pragma unroll
            for (int c = 0; c < 6; ++c) ob[c] = bw[c * KPAD + k] * vf;
            out_bidx[b * MAXOUT + s] = (float)b;
        }
    }
}

// ---------------- K1: rank -> (barrier) -> build -> (barrier) -> walk -------
__global__ __launch_bounds__(256, 1) void detect_kernel(
        const float* __restrict__ scores, const float* __restrict__ proposals,
        const float* __restrict__ deltas,
        int* __restrict__ order, float* __restrict__ boxes_ws,
        unsigned short* __restrict__ rowBits,
        int* __restrict__ g_idx, float* __restrict__ g_valid,
        float* __restrict__ out_boxes, float* __restrict__ out_bidx,
        uint32_t* __restrict__ cells) {
    extern __shared__ __align__(16) char smem[];
    int blk = blockIdx.x;
    int tid = threadIdx.x;

    if (blk < 128)
        dev_rank(blk >> 5, blk & 31, tid, (float*)smem, scores, proposals, deltas,
                 order, boxes_ws);
    grid_barrier(cells + 0, tid);

    // XCD-swizzled build: batch b's rows 0..511 land on XCD b (walk block b local)
    {
        int xcd = blk & 7;
        int batch = xcd & 3;
        int kbase = (((xcd >> 2) << 5) + (blk >> 3)) << 4;
        dev_build(batch, kbase, tid, (float(*)[1088])smem, boxes_ws, rowBits);
    }
    grid_barrier(cells + 1, tid);

    if (blk < BB)
        dev_walk(blk, tid, (unsigned short*)smem, rowBits, order, boxes_ws,
                 out_boxes, out_bidx, g_idx, g_valid);
}

// ---------------- K2: mask gather + trilinear 28^3 -> 32^3 (R4-proven) ------
__global__ __launch_bounds__(256) void resize_kernel(const float* __restrict__ masks,
                                                     const int* __restrict__ g_idx,
                                                     const float* __restrict__ g_valid,
                                                     float* __restrict__ out_masks) {
    int s = blockIdx.x;
    int b = s >> 7;
    int gi = g_idx[s];
    float vf = g_valid[s];
    const float* src = masks + (size_t)(b * NN + gi) * MASK_IN_VOX;
    float* dst = out_masks + (size_t)s * MASK_OUT_VOX;

    __shared__ __align__(16) float rowbuf[4][64 * 36];
    int tid = threadIdx.x;
    int lane = tid & 63;
    float* rb = rowbuf[tid >> 6];
    const float4* s4b = (const float4*)src;

#pragma unroll
    for (int p = 0; p < 4; ++p) {
        int idx = p * 256 + tid;
        int oy = idx & 31, oz = idx >> 5;

        float syf = 0.875f * oy - 0.0625f;
        int fly = (syf >= 0.f) ? (int)syf : -1;
        float fy = syf - (float)fly;
        int y0 = fly < 0 ? 0 : fly;
        int y1 = fly + 1 > 27 ? 27 : fly + 1;

        float szf = 0.875f * oz - 0.0625f;
        int flz = (szf >= 0.f) ? (int)szf : -1;
        float fz = szf - (float)flz;
        int z0 = flz < 0 ? 0 : flz;
        int z1 = flz + 1 > 27 ? 27 : flz + 1;

        float w00 = (1.f - fy) * (1.f - fz);
        float w01 = fy * (1.f - fz);
        float w10 = (1.f - fy) * fz;
        float w11 = fy * fz;

        const float4* r00 = s4b + (z0 * 28 + y0) * 7;
        const float4* r01 = s4b + (z0 * 28 + y1) * 7;
        const float4* r10 = s4b + (z1 * 28 + y0) * 7;
        const float4* r11 = s4b + (z1 * 28 + y1) * 7;

        float c[28];
#pragma unroll
        for (int t = 0; t < 7; ++t) {
            float4 a = r00[t], bb = r01[t], cc = r10[t], dd = r11[t];
            c[4 * t + 0] = a.x * w00 + bb.x * w01 + cc.x * w10 + dd.x * w11;
            c[4 * t + 1] = a.y * w00 + bb.y * w01 + cc.y * w10 + dd.y * w11;
            c[4 * t + 2] = a.z * w00 + bb.z * w01 + cc.z * w10 + dd.z * w11;
            c[4 * t + 3] = a.w * w00 + bb.w * w01 + cc.w * w10 + dd.w * w11;
        }

#pragma unroll
        for (int e = 0; e < 8; ++e) {
            float4 o;
#pragma unroll
            for (int qq = 0; qq < 4; ++qq) {
                const int ox = e * 4 + qq;
                const float sx = 0.875f * (float)ox - 0.0625f;
                const int flx = (ox == 0) ? -1 : (14 * ox - 1) / 16;
                const float fx = sx - (float)flx;
                const int x0 = flx < 0 ? 0 : flx;
                const int x1 = flx + 1 > 27 ? 27 : flx + 1;
                (&o.x)[qq] = (c[x0] + fx * (c[x1] - c[x0])) * vf;
            }
            *(float4*)&rb[lane * 36 + e * 4] = o;
        }

        float4* dchunk = (float4*)dst + (size_t)(p * 256 + (tid & ~63)) * 8;
#pragma unroll
        for (int t = 0; t < 8; ++t) {
            int f = t * 64 + lane;
            float4 v = *(const float4*)&rb[(f >> 3) * 36 + (f & 7) * 4];
            dchunk[f] = v;
        }
    }
}

// ---------------- launch ----------------------------------------------------
extern "C" void kernel_launch(void* const* d_in, const int* in_sizes, int n_in,
                              void* d_out, int out_size, void* d_ws, size_t ws_size,
                              hipStream_t stream) {
    const float* proposals = (const float*)d_in[0];
    const float* scores    = (const float*)d_in[1];
    const float* deltas    = (const float*)d_in[2];
    const float* masks     = (const float*)d_in[3];

    float* out = (float*)d_out;
    float* out_boxes = out;                                              // [512,6]
    float* out_masks = out + (size_t)BB * MAXOUT * 6;                    // [512,32768]
    float* out_bidx  = out + (size_t)BB * MAXOUT * 6 + (size_t)BB * MAXOUT * MASK_OUT_VOX;

    char* ws = (char*)d_ws;
    int*            order    = (int*)(ws);                               // 16 KB
    int*            g_idx    = (int*)(ws + (16 << 10));                  // 2 KB
    float*          g_valid  = (float*)(ws + (18 << 10));                // 2 KB
    float*          boxes_ws = (float*)(ws + (20 << 10));                // 96 KB
    unsigned short* rowBits  = (unsigned short*)(ws + (116 << 10));      // 512 KB
    // barrier cells: unused tail of batch-0's order block (ranks 1020..1023)
    uint32_t*       cells    = (uint32_t*)(ws + 1020 * sizeof(int));

    hipMemsetAsync(cells, 0, 16, stream);   // zero barrier cells every call

    detect_kernel<<<256, 256, K1_LDS, stream>>>(scores, proposals, deltas,
                                                order, boxes_ws, rowBits,
                                                g_idx, g_valid, out_boxes, out_bidx,
                                                cells);
    resize_kernel<<<BB * MAXOUT, 256, 0, stream>>>(masks, g_idx, g_valid, out_masks);
}